// Round 10
// baseline (152.602 us; speedup 1.0000x reference)
//
#include <hip/hip_runtime.h>

// Problem dims (fixed): S=256, BT=32, D=128, N=128, O=128
#define S_DIM 256
#define BT_DIM 32
#define D_DIM 128
#define N_DIM 128
#define O_DIM 128
#define SB (S_DIM * BT_DIM)   // 8192 flattened (s,b) rows
#define EPS 1e-7f

typedef short s16x8 __attribute__((ext_vector_type(8)));  // 8 bf16 (4 VGPRs)
typedef float fx4   __attribute__((ext_vector_type(4)));

union U8 { unsigned short u[8]; s16x8 v; };

__device__ __forceinline__ unsigned short f2bf(float f) {
    unsigned u = __builtin_bit_cast(unsigned, f);
    return (unsigned short)((u + 0x7fffu + ((u >> 16) & 1u)) >> 16);  // RNE
}
__device__ __forceinline__ float bf2f(unsigned short h) {
    unsigned u = ((unsigned)h) << 16;
    return __builtin_bit_cast(float, u);
}
// 8 fp32 -> bf16 (hi only)
__device__ __forceinline__ s16x8 cvt8hi(const float4 f0, const float4 f1) {
    float f[8] = {f0.x, f0.y, f0.z, f0.w, f1.x, f1.y, f1.z, f1.w};
    U8 h;
    #pragma unroll
    for (int i = 0; i < 8; ++i) h.u[i] = f2bf(f[i]);
    return h.v;
}
// 8 fp32 -> bf16 hi + lo fragments
__device__ __forceinline__ void cvt8(const float4 f0, const float4 f1, s16x8& hi, s16x8& lo) {
    float f[8] = {f0.x, f0.y, f0.z, f0.w, f1.x, f1.y, f1.z, f1.w};
    U8 h, l;
    #pragma unroll
    for (int i = 0; i < 8; ++i) {
        unsigned short hb = f2bf(f[i]);
        h.u[i] = hb;
        l.u[i] = f2bf(f[i] - bf2f(hb));
    }
    hi = h.v; lo = l.v;
}
// 4 fp32 -> bf16 hi + lo packed pairs
__device__ __forceinline__ void pack4(const float4 f, unsigned* hi2, unsigned* lo2) {
    float f_[4] = {f.x, f.y, f.z, f.w};
    unsigned short hb[4], lb[4];
    #pragma unroll
    for (int i = 0; i < 4; ++i) {
        hb[i] = f2bf(f_[i]);
        lb[i] = f2bf(f_[i] - bf2f(hb[i]));
    }
    hi2[0] = (unsigned)hb[0] | ((unsigned)hb[1] << 16);
    hi2[1] = (unsigned)hb[2] | ((unsigned)hb[3] << 16);
    lo2[0] = (unsigned)lb[0] | ((unsigned)lb[1] << 16);
    lo2[1] = (unsigned)lb[2] | ((unsigned)lb[3] << 16);
}

// ---------------------------------------------------------------------------
// Single fused kernel, 256 blocks x 512 thr = (b 32) x (nt 8).
// Phase P: Bx-tile = X@B^T (split-bf16 MFMA) -> two-level scan -> hs_hi + hT.
// Ticket + SPIN: every block increments cnt[b] (release-fenced) then waits
//   for cnt[b]==8. Deadlock-free by CAPACITY: 256 blocks at VGPR<=128
//   (__launch_bounds__(512,4)) -> >=2 blocks/CU -> all blocks co-resident,
//   producers always progress. Spin is short (siblings do identical work).
// Phase C: ALL 8 blocks of b participate: block (b,nt) computes out rows
//   s in [nt*32, nt*32+32) for its b -> full-machine spread (R8's fix).
// ---------------------------------------------------------------------------
__global__ __launch_bounds__(512, 4) void fused_lru(const float* __restrict__ X,
                                                    const float* __restrict__ lamlog,
                                                    const float* __restrict__ Bm,
                                                    const float* __restrict__ Cm,
                                                    unsigned* __restrict__ cnt,
                                                    unsigned short* __restrict__ hs_hi,
                                                    float* __restrict__ out,
                                                    float* __restrict__ hT) {
    __shared__ unsigned short Bhi[16][136];
    __shared__ unsigned short Blo[16][136];
    __shared__ float Bxs[S_DIM][17];
    __shared__ float carr[16][17];

    const int t  = threadIdx.x;
    const int b  = blockIdx.x >> 3;
    const int nt = blockIdx.x & 7;
    const int n0 = nt * 16;

    // ---- Phase P: stage + convert B tile (rows n0..n0+15), coalesced ----
    {
        const int row = t >> 5, c4 = t & 31;
        const float4 f = *reinterpret_cast<const float4*>(Bm + (size_t)(n0 + row) * D_DIM + c4 * 4);
        unsigned hi2[2], lo2[2];
        pack4(f, hi2, lo2);
        *reinterpret_cast<uint2*>(&Bhi[row][c4 * 4]) = make_uint2(hi2[0], hi2[1]);
        *reinterpret_cast<uint2*>(&Blo[row][c4 * 4]) = make_uint2(lo2[0], lo2[1]);
    }
    __syncthreads();

    const int w  = t >> 6, l = t & 63;   // w: 0..7
    const int lr = l & 15;               // frag row
    const int lk = (l >> 4) * 8;         // frag k-offset base

    {
        s16x8 bh[4], bl[4];
        #pragma unroll
        for (int sl = 0; sl < 4; ++sl) {
            bh[sl] = *reinterpret_cast<const s16x8*>(&Bhi[lr][sl * 32 + lk]);
            bl[sl] = *reinterpret_cast<const s16x8*>(&Blo[lr][sl * 32 + lk]);
        }

        const float* __restrict__ xb = X + (size_t)b * D_DIM;
        #pragma unroll
        for (int q = 0; q < 2; ++q) {
            const int s0 = (w * 2 + q) * 16;
            const float* __restrict__ xr = xb + (size_t)(s0 + lr) * (BT_DIM * D_DIM);
            s16x8 ah[4];
            #pragma unroll
            for (int sl = 0; sl < 4; ++sl) {
                const float4 f0 = *reinterpret_cast<const float4*>(xr + sl * 32 + lk);
                const float4 f1 = *reinterpret_cast<const float4*>(xr + sl * 32 + lk + 4);
                ah[sl] = cvt8hi(f0, f1);
            }
            fx4 acc = {0.f, 0.f, 0.f, 0.f};
            #pragma unroll
            for (int sl = 0; sl < 4; ++sl) {
                acc = __builtin_amdgcn_mfma_f32_16x16x32_bf16(ah[sl], bh[sl], acc, 0, 0, 0);
                acc = __builtin_amdgcn_mfma_f32_16x16x32_bf16(ah[sl], bl[sl], acc, 0, 0, 0);
            }
            #pragma unroll
            for (int r = 0; r < 4; ++r)
                Bxs[s0 + (l >> 4) * 4 + r][lr] = acc[r];
        }
    }
    __syncthreads();

    // ---- Two-level scan: 256 tasks on waves 0..3 (j = n-in-tile, c = chunk) ----
    {
        const int j = t & 15;
        const int c = (t >> 4) & 15;
        float lam = 0.f, gamma = 0.f, lam16 = 0.f;
        if (t < 256) {
            const float ll = lamlog[n0 + j];
            lam   = expf(-expf(ll));
            gamma = sqrtf(1.f - lam * lam + EPS);
            const float l2 = lam * lam, l4 = l2 * l2, l8 = l4 * l4;
            lam16 = l8 * l8;

            float h = 0.f;
            #pragma unroll
            for (int i = 0; i < 16; ++i)
                h = fmaf(lam, h, gamma * Bxs[c * 16 + i][j]);
            carr[c][j] = h;
        }
        __syncthreads();
        if (t < 256) {
            // static predicated prefix (replaces dynamic cp<c loop: ~2000 -> ~130 cyc)
            float carrv[16];
            #pragma unroll
            for (int cp = 0; cp < 16; ++cp) carrv[cp] = carr[cp][j];
            float Hb = 0.f;
            #pragma unroll
            for (int cp = 0; cp < 16; ++cp)
                if (cp < c) Hb = fmaf(lam16, Hb, carrv[cp]);

            float h = Hb;
            #pragma unroll
            for (int i = 0; i < 16; ++i) {
                h = fmaf(lam, h, gamma * Bxs[c * 16 + i][j]);
                const size_t rg = (size_t)(c * 16 + i) * BT_DIM + b;     // global row
                hs_hi[rg * N_DIM + n0 + j] = f2bf(h);
            }
            if (c == 15) hT[b * N_DIM + n0 + j] = h;
        }
    }

    // ---- Ticket + spin (R8-validated fencing; R8's policy bug fixed) ----
    __syncthreads();                 // all waves' stores drained (barrier waits vmcnt)
    __threadfence();                 // device-scope release
    __syncthreads();
    if (t == 0) {
        atomicAdd(&cnt[b], 1u);
        while (__hip_atomic_load(&cnt[b], __ATOMIC_RELAXED, __HIP_MEMORY_SCOPE_AGENT) < 8u)
            __builtin_amdgcn_s_sleep(8);
    }
    __syncthreads();                 // release all waves once cnt[b]==8
    __threadfence();                 // device-scope acquire

    // ---- Phase C: out rows s in [nt*32, nt*32+32) for this b ----
    // Wave w: s-tile st = w>>2 (0/1), o-tiles {2*(w&3), 2*(w&3)+1}.
    const int st = w >> 2;
    const int op = w & 3;
    const int s0 = nt * 32 + st * 16;

    s16x8 ch[2][4], cl[2][4];
    #pragma unroll
    for (int j2 = 0; j2 < 2; ++j2) {
        const int o0 = (2 * op + j2) * 16;
        const float* __restrict__ cr = Cm + (size_t)(o0 + lr) * N_DIM;
        #pragma unroll
        for (int sl = 0; sl < 4; ++sl) {
            const float4 f0 = *reinterpret_cast<const float4*>(cr + sl * 32 + lk);
            const float4 f1 = *reinterpret_cast<const float4*>(cr + sl * 32 + lk + 4);
            cvt8(f0, f1, ch[j2][sl], cl[j2][sl]);
        }
    }

    const unsigned short* __restrict__ hr =
        hs_hi + ((size_t)(s0 + lr) * BT_DIM + b) * N_DIM;
    s16x8 ah[4];
    #pragma unroll
    for (int sl = 0; sl < 4; ++sl)
        ah[sl] = *reinterpret_cast<const s16x8*>(&hr[sl * 32 + lk]);

    #pragma unroll
    for (int j2 = 0; j2 < 2; ++j2) {
        fx4 acc = {0.f, 0.f, 0.f, 0.f};
        #pragma unroll
        for (int sl = 0; sl < 4; ++sl) {
            acc = __builtin_amdgcn_mfma_f32_16x16x32_bf16(ah[sl], ch[j2][sl], acc, 0, 0, 0);
            acc = __builtin_amdgcn_mfma_f32_16x16x32_bf16(ah[sl], cl[j2][sl], acc, 0, 0, 0);
        }
        const int o0 = (2 * op + j2) * 16;
        const int sw = s0 + (l >> 4) * 4;
        #pragma unroll
        for (int r = 0; r < 4; ++r)
            out[((size_t)(sw + r) * BT_DIM + b) * O_DIM + o0 + lr] = acc[r];
    }
}

extern "C" void kernel_launch(void* const* d_in, const int* in_sizes, int n_in,
                              void* d_out, int out_size, void* d_ws, size_t ws_size,
                              hipStream_t stream) {
    const float* x          = (const float*)d_in[0];  // [S][BT][D]
    const float* lambda_log = (const float*)d_in[1];  // [N]
    const float* B          = (const float*)d_in[2];  // [N][D]
    const float* C          = (const float*)d_in[3];  // [O][N]

    float* out = (float*)d_out;                       // [S][BT][O] then hT [BT][N]
    float* hT  = out + (size_t)SB * O_DIM;

    unsigned* cnt = (unsigned*)d_ws;                              // 32 counters
    unsigned short* hs_hi = (unsigned short*)((char*)d_ws + 256); // [SB][N] bf16, 2 MB

    hipMemsetAsync(cnt, 0, 128, stream);              // zero tickets (ws is re-poisoned)
    fused_lru<<<256, 512, 0, stream>>>(x, lambda_log, B, C, cnt, hs_hi, out, hT);
}

// Round 11
// 72.558 us; speedup vs baseline: 2.1032x; 2.1032x over previous
//
#include <hip/hip_runtime.h>

// Problem dims (fixed): S=256, BT=32, D=128, N=128, O=128
#define S_DIM 256
#define BT_DIM 32
#define D_DIM 128
#define N_DIM 128
#define O_DIM 128
#define SB (S_DIM * BT_DIM)   // 8192 flattened (s,b) rows
#define EPS 1e-7f

typedef short s16x8 __attribute__((ext_vector_type(8)));  // 8 bf16 (4 VGPRs)
typedef float fx4   __attribute__((ext_vector_type(4)));

union U8 { unsigned short u[8]; s16x8 v; };

__device__ __forceinline__ unsigned short f2bf(float f) {
    unsigned u = __builtin_bit_cast(unsigned, f);
    return (unsigned short)((u + 0x7fffu + ((u >> 16) & 1u)) >> 16);  // RNE
}
__device__ __forceinline__ float bf2f(unsigned short h) {
    unsigned u = ((unsigned)h) << 16;
    return __builtin_bit_cast(float, u);
}
// 8 fp32 -> bf16 (hi only)
__device__ __forceinline__ s16x8 cvt8hi(const float4 f0, const float4 f1) {
    float f[8] = {f0.x, f0.y, f0.z, f0.w, f1.x, f1.y, f1.z, f1.w};
    U8 h;
    #pragma unroll
    for (int i = 0; i < 8; ++i) h.u[i] = f2bf(f[i]);
    return h.v;
}
// 4 fp32 -> bf16 hi + lo packed pairs
__device__ __forceinline__ void pack4(const float4 f, unsigned* hi2, unsigned* lo2) {
    float f_[4] = {f.x, f.y, f.z, f.w};
    unsigned short hb[4], lb[4];
    #pragma unroll
    for (int i = 0; i < 4; ++i) {
        hb[i] = f2bf(f_[i]);
        lb[i] = f2bf(f_[i] - bf2f(hb[i]));
    }
    hi2[0] = (unsigned)hb[0] | ((unsigned)hb[1] << 16);
    hi2[1] = (unsigned)hb[2] | ((unsigned)hb[3] << 16);
    lo2[0] = (unsigned)lb[0] | ((unsigned)lb[1] << 16);
    lo2[1] = (unsigned)lb[2] | ((unsigned)lb[3] << 16);
}

// ---------------------------------------------------------------------------
// K1: Bx = X @ B^T (split-bf16 MFMA: Xhi*Bhi + Xhi*Blo) -> two-level scan.
// Blocks 0..255: (b 32) x (nt 8), 256 thr = 4 waves; wave w owns 4 s-tiles.
// XCD SWIZZLE: b = (bid&7)*4 + (bid>>6), nt = (bid>>3)&7 -- the 8 siblings of
//   each b share bid%8, i.e. land on ONE XCD (round-robin dispatch), so the
//   shared 128 KB X-slice is fetched into that XCD's L2 once, 7 blocks hit.
// Blocks 256..263: one-time C -> bf16 hi/lo conversion into ws (for K2).
// hs stored bf16 (hi only) row-major [r][n].
// ---------------------------------------------------------------------------
__global__ __launch_bounds__(256) void k1_gemm_scan(const float* __restrict__ X,
                                                    const float* __restrict__ lamlog,
                                                    const float* __restrict__ Bm,
                                                    const float* __restrict__ Cm,
                                                    unsigned short* __restrict__ hs_hi,
                                                    unsigned short* __restrict__ Chi,
                                                    unsigned short* __restrict__ Clo,
                                                    float* __restrict__ hT) {
    const int t = threadIdx.x;

    if (blockIdx.x >= 256) {
        // C-convert: 8 blocks x 256 thr x 8 elems = 16384 = 128*128.
        const int id = (blockIdx.x - 256) * 256 + t;            // 0..2047
        const float4 f0 = reinterpret_cast<const float4*>(Cm)[id * 2];
        const float4 f1 = reinterpret_cast<const float4*>(Cm)[id * 2 + 1];
        unsigned h0[2], l0[2], h1[2], l1[2];
        pack4(f0, h0, l0);
        pack4(f1, h1, l1);
        *reinterpret_cast<uint4*>(Chi + (size_t)id * 8) = make_uint4(h0[0], h0[1], h1[0], h1[1]);
        *reinterpret_cast<uint4*>(Clo + (size_t)id * 8) = make_uint4(l0[0], l0[1], l1[0], l1[1]);
        return;
    }

    __shared__ unsigned short Bhi[16][136];
    __shared__ unsigned short Blo[16][136];
    __shared__ float Bxs[S_DIM][17];
    __shared__ float carr[16][17];

    // XCD-locality swizzle (bijective on [0,256))
    const int d  = blockIdx.x;
    const int b  = (d & 7) * 4 + (d >> 6);
    const int n0 = ((d >> 3) & 7) * 16;

    // Stage + convert B tile (rows n0..n0+15): 512 float4, 2/thread, coalesced.
    #pragma unroll
    for (int q = 0; q < 2; ++q) {
        const int id4 = t + 256 * q;
        const int row = id4 >> 5, c4 = id4 & 31;
        const float4 f = *reinterpret_cast<const float4*>(Bm + (size_t)(n0 + row) * D_DIM + c4 * 4);
        unsigned hi2[2], lo2[2];
        pack4(f, hi2, lo2);
        *reinterpret_cast<uint2*>(&Bhi[row][c4 * 4]) = make_uint2(hi2[0], hi2[1]);
        *reinterpret_cast<uint2*>(&Blo[row][c4 * 4]) = make_uint2(lo2[0], lo2[1]);
    }
    __syncthreads();

    const int w  = t >> 6, l = t & 63;
    const int lr = l & 15;            // frag row
    const int lk = (l >> 4) * 8;      // frag k-offset base

    {
        s16x8 bh[4], bl[4];
        #pragma unroll
        for (int sl = 0; sl < 4; ++sl) {
            bh[sl] = *reinterpret_cast<const s16x8*>(&Bhi[lr][sl * 32 + lk]);
            bl[sl] = *reinterpret_cast<const s16x8*>(&Blo[lr][sl * 32 + lk]);
        }

        const float* __restrict__ xb = X + (size_t)b * D_DIM;
        #pragma unroll
        for (int q = 0; q < 4; ++q) {
            const int s0 = (w * 4 + q) * 16;
            const float* __restrict__ xr = xb + (size_t)(s0 + lr) * (BT_DIM * D_DIM);
            s16x8 ah[4];
            #pragma unroll
            for (int sl = 0; sl < 4; ++sl) {
                const float4 f0 = *reinterpret_cast<const float4*>(xr + sl * 32 + lk);
                const float4 f1 = *reinterpret_cast<const float4*>(xr + sl * 32 + lk + 4);
                ah[sl] = cvt8hi(f0, f1);
            }
            fx4 acc = {0.f, 0.f, 0.f, 0.f};
            #pragma unroll
            for (int sl = 0; sl < 4; ++sl) {
                acc = __builtin_amdgcn_mfma_f32_16x16x32_bf16(ah[sl], bh[sl], acc, 0, 0, 0);
                acc = __builtin_amdgcn_mfma_f32_16x16x32_bf16(ah[sl], bl[sl], acc, 0, 0, 0);
            }
            #pragma unroll
            for (int r = 0; r < 4; ++r)
                Bxs[s0 + (l >> 4) * 4 + r][lr] = acc[r];
        }
    }
    __syncthreads();

    // Two-level scan: 256 tasks (j = n-within-tile, c = 16-step chunk).
    const int j = t & 15;
    const int c = t >> 4;
    const float ll    = lamlog[n0 + j];
    const float lam   = expf(-expf(ll));
    const float gamma = sqrtf(1.f - lam * lam + EPS);
    const float l2 = lam * lam, l4 = l2 * l2, l8 = l4 * l4;
    const float lam16 = l8 * l8;

    float h = 0.f;
    #pragma unroll
    for (int i = 0; i < 16; ++i)
        h = fmaf(lam, h, gamma * Bxs[c * 16 + i][j]);
    carr[c][j] = h;
    __syncthreads();

    // static predicated prefix (no serial dependent-LDS chain)
    float carrv[16];
    #pragma unroll
    for (int cp = 0; cp < 16; ++cp) carrv[cp] = carr[cp][j];
    float Hb = 0.f;
    #pragma unroll
    for (int cp = 0; cp < 16; ++cp)
        if (cp < c) Hb = fmaf(lam16, Hb, carrv[cp]);

    h = Hb;
    #pragma unroll
    for (int i = 0; i < 16; ++i) {
        h = fmaf(lam, h, gamma * Bxs[c * 16 + i][j]);
        const size_t rg = (size_t)(c * 16 + i) * BT_DIM + b;     // global row
        hs_hi[rg * N_DIM + n0 + j] = f2bf(h);
    }
    if (c == 15) hT[b * N_DIM + n0 + j] = h;
}

// ---------------------------------------------------------------------------
// K2: out = hs @ C^T  (hs_hi * Chi + hs_hi * Clo).
// 256 blocks x 256 thr (4 waves); block = 32 rows x 128 o.
// hs tile (8 KB) staged into LDS with fully-coalesced 32B/thread loads
// (fixes 25% cache-line efficiency of direct per-lane strided reads);
// fragments then read from LDS (pad 136 shorts -> 2-way alias, free).
// C fragments direct from global (Chi/Clo 32 KB each, L2-resident).
// ---------------------------------------------------------------------------
__global__ __launch_bounds__(256) void k2_outgemm(const unsigned short* __restrict__ hs_hi,
                                                  const unsigned short* __restrict__ Chi,
                                                  const unsigned short* __restrict__ Clo,
                                                  float* __restrict__ out) {
    __shared__ unsigned short Hs[32][136];   // 8.5 KB

    const int t  = threadIdx.x;
    const int r0 = blockIdx.x * 32;

    // Stage hs rows r0..r0+31: thread t -> row t>>3, 32B chunk t&7 (coalesced).
    {
        const int row = t >> 3, ch = t & 7;
        const unsigned short* src = hs_hi + (size_t)(r0 + row) * N_DIM + ch * 16;
        *reinterpret_cast<uint4*>(&Hs[row][ch * 16])     = *reinterpret_cast<const uint4*>(src);
        *reinterpret_cast<uint4*>(&Hs[row][ch * 16 + 8]) = *reinterpret_cast<const uint4*>(src + 8);
    }
    __syncthreads();

    const int w  = t >> 6, l = t & 63;
    const int lr = l & 15;
    const int lk = (l >> 4) * 8;
    const int rt = w & 1;

    // A-fragments from LDS: contiguous 16 B per lane, 2-way bank alias (free).
    s16x8 ah[4];
    #pragma unroll
    for (int sl = 0; sl < 4; ++sl)
        ah[sl] = *reinterpret_cast<const s16x8*>(&Hs[16 * rt + lr][sl * 32 + lk]);

    #pragma unroll
    for (int q = 0; q < 4; ++q) {
        const int o0 = (w >> 1) * 64 + q * 16;
        fx4 acc = {0.f, 0.f, 0.f, 0.f};
        #pragma unroll
        for (int sl = 0; sl < 4; ++sl) {
            const s16x8 bh = *reinterpret_cast<const s16x8*>(&Chi[(size_t)(o0 + lr) * N_DIM + sl * 32 + lk]);
            const s16x8 bl = *reinterpret_cast<const s16x8*>(&Clo[(size_t)(o0 + lr) * N_DIM + sl * 32 + lk]);
            acc = __builtin_amdgcn_mfma_f32_16x16x32_bf16(ah[sl], bh, acc, 0, 0, 0);
            acc = __builtin_amdgcn_mfma_f32_16x16x32_bf16(ah[sl], bl, acc, 0, 0, 0);
        }
        const int rw = r0 + 16 * rt + (l >> 4) * 4;
        #pragma unroll
        for (int r = 0; r < 4; ++r)
            out[(size_t)(rw + r) * O_DIM + o0 + lr] = acc[r];
    }
}

extern "C" void kernel_launch(void* const* d_in, const int* in_sizes, int n_in,
                              void* d_out, int out_size, void* d_ws, size_t ws_size,
                              hipStream_t stream) {
    const float* x          = (const float*)d_in[0];  // [S][BT][D]
    const float* lambda_log = (const float*)d_in[1];  // [N]
    const float* B          = (const float*)d_in[2];  // [N][D]
    const float* C          = (const float*)d_in[3];  // [O][N]

    float* out = (float*)d_out;                       // [S][BT][O] then hT [BT][N]
    float* hT  = out + (size_t)SB * O_DIM;

    unsigned short* hs_hi = (unsigned short*)d_ws;            // [SB][N] bf16, 2 MB
    unsigned short* Chi   = hs_hi + (size_t)SB * N_DIM;       // [O][N] bf16, 32 KB
    unsigned short* Clo   = Chi + O_DIM * N_DIM;              // [O][N] bf16, 32 KB

    // K1 (+8 tail blocks pre-converting C for K2)
    k1_gemm_scan<<<264, 256, 0, stream>>>(x, lambda_log, B, C, hs_hi, Chi, Clo, hT);
    // K2
    k2_outgemm<<<256, 256, 0, stream>>>(hs_hi, Chi, Clo, out);
}

// Round 12
// 69.341 us; speedup vs baseline: 2.2008x; 1.0464x over previous
//
#include <hip/hip_runtime.h>

// Problem dims (fixed): S=256, BT=32, D=128, N=128, O=128
#define S_DIM 256
#define BT_DIM 32
#define D_DIM 128
#define N_DIM 128
#define O_DIM 128
#define SB (S_DIM * BT_DIM)   // 8192 flattened (s,b) rows
#define EPS 1e-7f

typedef short s16x8 __attribute__((ext_vector_type(8)));  // 8 bf16 (4 VGPRs)
typedef float fx4   __attribute__((ext_vector_type(4)));

// HW packed f32->bf16 convert (gfx950; no builtin -> inline asm).
// dst low16 = bf16(a), dst high16 = bf16(b).
__device__ __forceinline__ unsigned pk_bf16(float a, float b) {
    unsigned r;
    asm("v_cvt_pk_bf16_f32 %0, %1, %2" : "=v"(r) : "v"(a), "v"(b));
    return r;
}
// 8 fp32 -> 8 bf16 (4 packed u32) via 4 HW converts
__device__ __forceinline__ s16x8 cvt8hi(const float4 f0, const float4 f1) {
    union { unsigned u[4]; s16x8 v; } r;
    r.u[0] = pk_bf16(f0.x, f0.y);
    r.u[1] = pk_bf16(f0.z, f0.w);
    r.u[2] = pk_bf16(f1.x, f1.y);
    r.u[3] = pk_bf16(f1.z, f1.w);
    return r.v;
}

// ---------------------------------------------------------------------------
// K1: Bx = X @ B^T (bf16 MFMA, hi-only operands) -> two-level scan.
// Blocks 0..255: (b 32) x (nt 8), 256 thr = 4 waves; wave w owns 4 s-tiles.
// XCD SWIZZLE: the 8 sibling blocks of each b share bid%8 -> one XCD ->
//   the shared 128 KB X-slice is L2-resident after the first fetch.
// Blocks 256..263: one-time C -> bf16 conversion into ws (for K2).
// hs stored bf16 row-major [r][n]. Error budget: bf16-B adds ~1e-3 to Bx
//   (sigma_B~0.088, rel 2^-9, sqrt(128) accum); scan is variance-preserving;
//   dominant error remains hs-bf16 rounding (~0.03 absmax) -- under 0.1025.
// ---------------------------------------------------------------------------
__global__ __launch_bounds__(256) void k1_gemm_scan(const float* __restrict__ X,
                                                    const float* __restrict__ lamlog,
                                                    const float* __restrict__ Bm,
                                                    const float* __restrict__ Cm,
                                                    unsigned short* __restrict__ hs_hi,
                                                    unsigned short* __restrict__ Chi,
                                                    float* __restrict__ hT) {
    const int t = threadIdx.x;

    if (blockIdx.x >= 256) {
        // C-convert: 8 blocks x 256 thr x 8 elems = 16384 = 128*128.
        const int id = (blockIdx.x - 256) * 256 + t;            // 0..2047
        const float4 f0 = reinterpret_cast<const float4*>(Cm)[id * 2];
        const float4 f1 = reinterpret_cast<const float4*>(Cm)[id * 2 + 1];
        *reinterpret_cast<uint4*>(Chi + (size_t)id * 8) =
            make_uint4(pk_bf16(f0.x, f0.y), pk_bf16(f0.z, f0.w),
                       pk_bf16(f1.x, f1.y), pk_bf16(f1.z, f1.w));
        return;
    }

    __shared__ unsigned short Bhi[16][136];
    __shared__ float Bxs[S_DIM][17];
    __shared__ float carr[16][17];

    // XCD-locality swizzle (bijective on [0,256))
    const int d  = blockIdx.x;
    const int b  = (d & 7) * 4 + (d >> 6);
    const int n0 = ((d >> 3) & 7) * 16;

    // Stage + convert B tile (rows n0..n0+15): 512 float4, 2/thread, coalesced.
    #pragma unroll
    for (int q = 0; q < 2; ++q) {
        const int id4 = t + 256 * q;
        const int row = id4 >> 5, c4 = id4 & 31;
        const float4 f = *reinterpret_cast<const float4*>(Bm + (size_t)(n0 + row) * D_DIM + c4 * 4);
        *reinterpret_cast<uint2*>(&Bhi[row][c4 * 4]) =
            make_uint2(pk_bf16(f.x, f.y), pk_bf16(f.z, f.w));
    }
    __syncthreads();

    const int w  = t >> 6, l = t & 63;
    const int lr = l & 15;            // frag row
    const int lk = (l >> 4) * 8;      // frag k-offset base

    {
        s16x8 bh[4];
        #pragma unroll
        for (int sl = 0; sl < 4; ++sl)
            bh[sl] = *reinterpret_cast<const s16x8*>(&Bhi[lr][sl * 32 + lk]);

        const float* __restrict__ xb = X + (size_t)b * D_DIM;
        #pragma unroll
        for (int q = 0; q < 4; ++q) {
            const int s0 = (w * 4 + q) * 16;
            const float* __restrict__ xr = xb + (size_t)(s0 + lr) * (BT_DIM * D_DIM);
            s16x8 ah[4];
            #pragma unroll
            for (int sl = 0; sl < 4; ++sl) {
                const float4 f0 = *reinterpret_cast<const float4*>(xr + sl * 32 + lk);
                const float4 f1 = *reinterpret_cast<const float4*>(xr + sl * 32 + lk + 4);
                ah[sl] = cvt8hi(f0, f1);
            }
            fx4 acc = {0.f, 0.f, 0.f, 0.f};
            #pragma unroll
            for (int sl = 0; sl < 4; ++sl)
                acc = __builtin_amdgcn_mfma_f32_16x16x32_bf16(ah[sl], bh[sl], acc, 0, 0, 0);
            #pragma unroll
            for (int r = 0; r < 4; ++r)
                Bxs[s0 + (l >> 4) * 4 + r][lr] = acc[r];
        }
    }
    __syncthreads();

    // Two-level scan: 256 tasks (j = n-within-tile, c = 16-step chunk).
    const int j = t & 15;
    const int c = t >> 4;
    const float ll    = lamlog[n0 + j];
    const float lam   = expf(-expf(ll));
    const float gamma = sqrtf(1.f - lam * lam + EPS);
    const float l2 = lam * lam, l4 = l2 * l2, l8 = l4 * l4;
    const float lam16 = l8 * l8;

    float h = 0.f;
    #pragma unroll
    for (int i = 0; i < 16; ++i)
        h = fmaf(lam, h, gamma * Bxs[c * 16 + i][j]);
    carr[c][j] = h;
    __syncthreads();

    // static predicated prefix (no serial dependent-LDS chain)
    float carrv[16];
    #pragma unroll
    for (int cp = 0; cp < 16; ++cp) carrv[cp] = carr[cp][j];
    float Hb = 0.f;
    #pragma unroll
    for (int cp = 0; cp < 16; ++cp)
        if (cp < c) Hb = fmaf(lam16, Hb, carrv[cp]);

    h = Hb;
    #pragma unroll
    for (int i = 0; i < 16; ++i) {
        h = fmaf(lam, h, gamma * Bxs[c * 16 + i][j]);
        const size_t rg = (size_t)(c * 16 + i) * BT_DIM + b;     // global row
        hs_hi[rg * N_DIM + n0 + j] = (unsigned short)pk_bf16(h, h);
    }
    if (c == 15) hT[b * N_DIM + n0 + j] = h;
}

// ---------------------------------------------------------------------------
// K2: out = hs @ C^T (bf16 MFMA, hi-only).
// 256 blocks x 256 thr (4 waves); block = 32 rows x 128 o.
// hs tile (8 KB) staged into LDS with fully-coalesced 32B/thread loads;
// fragments read from LDS (pad 136 shorts -> 2-way alias, free).
// C fragments direct from global (Chi 32 KB, L2-resident).
// ---------------------------------------------------------------------------
__global__ __launch_bounds__(256) void k2_outgemm(const unsigned short* __restrict__ hs_hi,
                                                  const unsigned short* __restrict__ Chi,
                                                  float* __restrict__ out) {
    __shared__ unsigned short Hs[32][136];   // 8.5 KB

    const int t  = threadIdx.x;
    const int r0 = blockIdx.x * 32;

    // Stage hs rows r0..r0+31: thread t -> row t>>3, 32B chunk t&7 (coalesced).
    {
        const int row = t >> 3, ch = t & 7;
        const unsigned short* src = hs_hi + (size_t)(r0 + row) * N_DIM + ch * 16;
        *reinterpret_cast<uint4*>(&Hs[row][ch * 16])     = *reinterpret_cast<const uint4*>(src);
        *reinterpret_cast<uint4*>(&Hs[row][ch * 16 + 8]) = *reinterpret_cast<const uint4*>(src + 8);
    }
    __syncthreads();

    const int w  = t >> 6, l = t & 63;
    const int lr = l & 15;
    const int lk = (l >> 4) * 8;
    const int rt = w & 1;

    // A-fragments from LDS: contiguous 16 B per lane.
    s16x8 ah[4];
    #pragma unroll
    for (int sl = 0; sl < 4; ++sl)
        ah[sl] = *reinterpret_cast<const s16x8*>(&Hs[16 * rt + lr][sl * 32 + lk]);

    #pragma unroll
    for (int q = 0; q < 4; ++q) {
        const int o0 = (w >> 1) * 64 + q * 16;
        fx4 acc = {0.f, 0.f, 0.f, 0.f};
        #pragma unroll
        for (int sl = 0; sl < 4; ++sl) {
            const s16x8 bh = *reinterpret_cast<const s16x8*>(&Chi[(size_t)(o0 + lr) * N_DIM + sl * 32 + lk]);
            acc = __builtin_amdgcn_mfma_f32_16x16x32_bf16(ah[sl], bh, acc, 0, 0, 0);
        }
        const int rw = r0 + 16 * rt + (l >> 4) * 4;
        #pragma unroll
        for (int r = 0; r < 4; ++r)
            out[(size_t)(rw + r) * O_DIM + o0 + lr] = acc[r];
    }
}

extern "C" void kernel_launch(void* const* d_in, const int* in_sizes, int n_in,
                              void* d_out, int out_size, void* d_ws, size_t ws_size,
                              hipStream_t stream) {
    const float* x          = (const float*)d_in[0];  // [S][BT][D]
    const float* lambda_log = (const float*)d_in[1];  // [N]
    const float* B          = (const float*)d_in[2];  // [N][D]
    const float* C          = (const float*)d_in[3];  // [O][N]

    float* out = (float*)d_out;                       // [S][BT][O] then hT [BT][N]
    float* hT  = out + (size_t)SB * O_DIM;

    unsigned short* hs_hi = (unsigned short*)d_ws;            // [SB][N] bf16, 2 MB
    unsigned short* Chi   = hs_hi + (size_t)SB * N_DIM;       // [O][N] bf16, 32 KB

    // K1 (+8 tail blocks pre-converting C for K2)
    k1_gemm_scan<<<264, 256, 0, stream>>>(x, lambda_log, B, C, hs_hi, Chi, hT);
    // K2
    k2_outgemm<<<256, 256, 0, stream>>>(hs_hi, Chi, out);
}